// Round 7
// baseline (395.958 us; speedup 1.0000x reference)
//
#include <hip/hip_runtime.h>
#include <hip/hip_bf16.h>
#include <stdint.h>

typedef int v4i __attribute__((ext_vector_type(4)));
typedef float v4f __attribute__((ext_vector_type(4)));

#define T_TOKENS 8192
#define KDIM 4096
#define NDIM 4096

#define BM 256
#define BN 256
#define BKB 128   // K-bytes per LDS tile = 2 k-steps of mfma_i32_16x16x64_i8

// ---------------------------------------------------------------------------
// Kernel 1: repack weight int32 -> int8 (harness widens integer inputs).
// ---------------------------------------------------------------------------
__global__ __launch_bounds__(256) void conv_w(const int* __restrict__ w32,
                                              int8_t* __restrict__ w8) {
    int idx = blockIdx.x * 256 + threadIdx.x;
    const v4i* src = (const v4i*)w32 + (size_t)idx * 4;
    v4i p;
#pragma unroll
    for (int q = 0; q < 4; ++q) {
        v4i s = src[q];
        p[q] = (s[0] & 255) | ((s[1] & 255) << 8) | ((s[2] & 255) << 16)
             | ((s[3] & 255) << 24);
    }
    ((v4i*)w8)[idx] = p;
}

// ---------------------------------------------------------------------------
// Kernel 2: per-token dynamic quantization (verified round 5).
// ---------------------------------------------------------------------------
__global__ __launch_bounds__(256) void quant_x(const float* __restrict__ x,
                                               int8_t* __restrict__ qx,
                                               float* __restrict__ xs) {
    int t = blockIdx.x;
    int tid = threadIdx.x;
    const v4f* xrow = (const v4f*)(x + (size_t)t * KDIM);

    v4f vals[4];
    float m = 0.f;
#pragma unroll
    for (int q = 0; q < 4; ++q) {
        v4f v = xrow[q * 256 + tid];
        vals[q] = v;
        m = fmaxf(m, fmaxf(fmaxf(fabsf(v[0]), fabsf(v[1])),
                           fmaxf(fabsf(v[2]), fabsf(v[3]))));
    }
#pragma unroll
    for (int off = 32; off > 0; off >>= 1)
        m = fmaxf(m, __shfl_xor(m, off));

    __shared__ float wmax[4];
    __shared__ float sh_scale;
    int wave = tid >> 6;
    if ((tid & 63) == 0) wmax[wave] = m;
    __syncthreads();
    if (tid == 0) {
        float mm = fmaxf(fmaxf(wmax[0], wmax[1]), fmaxf(wmax[2], wmax[3]));
        float sc = mm / 127.0f;
        sh_scale = sc;
        xs[t] = sc;
    }
    __syncthreads();
    float sc = sh_scale;

    unsigned int* qrow = (unsigned int*)(qx + (size_t)t * KDIM);
#pragma unroll
    for (int q = 0; q < 4; ++q) {
        unsigned int packed = 0;
#pragma unroll
        for (int j = 0; j < 4; ++j) {
            float fq = rintf(vals[q][j] / sc);
            fq = fminf(fmaxf(fq, -128.f), 127.f);
            int b = (int)fq;
            packed |= ((unsigned int)(unsigned char)(b & 0xff)) << (8 * j);
        }
        qrow[q * 256 + tid] = packed;
    }
}

// ---------------------------------------------------------------------------
// Kernel 3: int8 GEMM, 256x256 tile, ONE barrier per K-tile, reg-pipelined.
// LDS 128KB = 2 bufs x [Ak0|Ak1|Bk0|Bk1] 16KB k-half panels.
// Per tile: (1) issue 8 global_load_lds for tile t+1 into the other buffer,
// (2) 24 ds_read_b128 (both k-halves), (3) 64 MFMA (F1 reads complete under
// F0's MFMA cluster), (4) vmcnt(0) [drains loads issued one tile-body ago,
// ~free] + s_barrier. Swizzle: slot' = kg ^ ((row>>1)&3) in 64B rows, applied
// on global source AND ds_read (both-sides rule) -> bank-conflict-free
// (verified: 0 conflicts in rounds 5/6).
// ---------------------------------------------------------------------------
__global__ __launch_bounds__(512, 2) void gemm_i8(
        const int8_t* __restrict__ A, const int8_t* __restrict__ B,
        const float* __restrict__ xs, const float* __restrict__ wscale,
        const float* __restrict__ bias, float* __restrict__ out) {
    __shared__ char lds[131072];   // 2 x 64KB

    const int tid  = threadIdx.x;
    const int lane = tid & 63;
    const int w    = tid >> 6;          // wave 0..7
    const int wr   = w >> 2;            // 0..1 (M)
    const int wc   = w & 3;             // 0..3 (N)
    const int lrow = lane & 15;
    const int kg   = lane >> 4;
    const int swz  = (kg ^ ((lrow >> 1) & 3)) << 4;   // read-side swizzle

    // XCD-aware bijective swizzle: 512 blocks, 8 XCDs, 64 per XCD
    int flat = blockIdx.x;
    int f2 = (flat & 7) * 64 + (flat >> 3);
    int bm = f2 >> 4, bn = f2 & 15;     // 32 x 16

    const int8_t* Ab = A + (size_t)bm * BM * KDIM;
    const int8_t* Bb = B + (size_t)bn * BN * KDIM;

    // staging: per load-round, wave w covers 16 rows (lane>>2) x 4 slots;
    // pre-swizzled source slot = (lane&3) ^ ((row>>1)&3) = (lane&3)^((lane>>3)&3)
    const int sg16 = (((lane & 3) ^ ((lane >> 3) & 3)) << 4);

    // stage one 256-row x 64B k-half panel (2 load-rounds of 128 rows)
#define STAGE_HALF(gp, kbyte, lhalf)                                             \
    do {                                                                         \
        _Pragma("unroll")                                                        \
        for (int r_ = 0; r_ < 2; ++r_) {                                         \
            int row_ = r_ * 128 + (w << 4) + (lane >> 2);                        \
            const int8_t* g_ = (gp) + (size_t)row_ * KDIM + (kbyte) + sg16;      \
            char* l_ = (lhalf) + (size_t)(r_ * 128 + (w << 4)) * 64;             \
            __builtin_amdgcn_global_load_lds(                                    \
                (const __attribute__((address_space(1))) void*)g_,               \
                (__attribute__((address_space(3))) void*)l_, 16, 0, 0);          \
        }                                                                        \
    } while (0)

    v4i acc[8][4] = {};

    // ---- prologue: stage tile 0 fully, drain once (cold) ----
    STAGE_HALF(Ab, 0,  lds + 0);
    STAGE_HALF(Ab, 64, lds + 16384);
    STAGE_HALF(Bb, 0,  lds + 32768);
    STAGE_HALF(Bb, 64, lds + 49152);
    asm volatile("s_waitcnt vmcnt(0)" ::: "memory");
    __builtin_amdgcn_s_barrier();
    asm volatile("" ::: "memory");

    const int abase = wr * 128 + lrow;   // A frag row base (+m*16)
    const int bbase = wc * 64 + lrow;    // B frag row base (+n*16)

    for (int t = 0; t < KDIM / BKB; ++t) {
        char* cur = lds + ((t & 1) << 16);
        char* nxt = lds + (((t + 1) & 1) << 16);
        int   nk  = ((t + 1) & 31) * BKB;

        // (1) early-issue next tile's 8 staging loads (other buffer)
        STAGE_HALF(Ab, nk,      nxt + 0);
        STAGE_HALF(Ab, nk + 64, nxt + 16384);
        STAGE_HALF(Bb, nk,      nxt + 32768);
        STAGE_HALF(Bb, nk + 64, nxt + 49152);

        // (2) fragment reads, both k-halves
        v4i f0a[8], f1a[8], f0b[4], f1b[4];
#pragma unroll
        for (int m = 0; m < 8; ++m)
            f0a[m] = *(const v4i*)(cur + (abase + m * 16) * 64 + swz);
#pragma unroll
        for (int n = 0; n < 4; ++n)
            f0b[n] = *(const v4i*)(cur + 32768 + (bbase + n * 16) * 64 + swz);
#pragma unroll
        for (int m = 0; m < 8; ++m)
            f1a[m] = *(const v4i*)(cur + 16384 + (abase + m * 16) * 64 + swz);
#pragma unroll
        for (int n = 0; n < 4; ++n)
            f1b[n] = *(const v4i*)(cur + 49152 + (bbase + n * 16) * 64 + swz);

        // (3) MFMA clusters; F1 ds_reads complete under F0's MFMAs
        __builtin_amdgcn_s_setprio(1);
#pragma unroll
        for (int m = 0; m < 8; ++m)
#pragma unroll
            for (int n = 0; n < 4; ++n)
                acc[m][n] = __builtin_amdgcn_mfma_i32_16x16x64_i8(
                    f0a[m], f0b[n], acc[m][n], 0, 0, 0);
#pragma unroll
        for (int m = 0; m < 8; ++m)
#pragma unroll
            for (int n = 0; n < 4; ++n)
                acc[m][n] = __builtin_amdgcn_mfma_i32_16x16x64_i8(
                    f1a[m], f1b[n], acc[m][n], 0, 0, 0);
        __builtin_amdgcn_s_setprio(0);

        // (4) single drain+barrier per tile; loads were issued 1 tile ago
        asm volatile("s_waitcnt vmcnt(0)" ::: "memory");
        __builtin_amdgcn_s_barrier();
        asm volatile("" ::: "memory");
    }

    // ---- epilogue: dequant + bias, FP32 output ----
    int rowg0 = bm * BM + wr * 128;
    int colg0 = bn * BN + wc * 64;
    float xsv[8][4];
#pragma unroll
    for (int m = 0; m < 8; ++m)
#pragma unroll
        for (int j = 0; j < 4; ++j)
            xsv[m][j] = xs[rowg0 + m * 16 + kg * 4 + j];

#pragma unroll
    for (int n = 0; n < 4; ++n) {
        int col = colg0 + n * 16 + lrow;
        float wsc = wscale[col];
        float bs  = bias[col];
#pragma unroll
        for (int m = 0; m < 8; ++m) {
#pragma unroll
            for (int j = 0; j < 4; ++j) {
                int row = rowg0 + m * 16 + kg * 4 + j;
                float y = (float)acc[m][n][j] * wsc * xsv[m][j] + bs;
                out[(size_t)row * NDIM + col] = y;
            }
        }
    }
#undef STAGE_HALF
}

// ---------------------------------------------------------------------------
extern "C" void kernel_launch(void* const* d_in, const int* in_sizes, int n_in,
                              void* d_out, int out_size, void* d_ws, size_t ws_size,
                              hipStream_t stream) {
    const float* x    = (const float*)d_in[0];     // fp16 promoted to fp32
    const int*   w32  = (const int*)d_in[1];       // int8 widened to int32
    const float* wsc  = (const float*)d_in[2];
    const float* bias = (const float*)d_in[3];
    float* out = (float*)d_out;

    int8_t* qx = (int8_t*)d_ws;
    int8_t* w8 = (int8_t*)d_ws + (size_t)T_TOKENS * KDIM;
    float*  xs = (float*)((int8_t*)d_ws + (size_t)T_TOKENS * KDIM + (size_t)NDIM * KDIM);

    hipLaunchKernelGGL(conv_w, dim3(NDIM * KDIM / 16 / 256), dim3(256), 0, stream, w32, w8);
    hipLaunchKernelGGL(quant_x, dim3(T_TOKENS), dim3(256), 0, stream, x, qx, xs);
    hipLaunchKernelGGL(gemm_i8, dim3((T_TOKENS / BM) * (NDIM / BN)), dim3(512), 0, stream,
                       qx, w8, xs, wsc, bias, out);
}